// Round 12
// baseline (229.870 us; speedup 1.0000x reference)
//
#include <hip/hip_runtime.h>
#include <hip/hip_bf16.h>
#include <stdint.h>
#include <math.h>

typedef unsigned short u16;
typedef __attribute__((ext_vector_type(8))) short short8;
typedef __attribute__((ext_vector_type(4))) float f32x4;
typedef __attribute__((ext_vector_type(16))) float f32x16;
typedef __attribute__((ext_vector_type(4))) unsigned int u32x4;
typedef __attribute__((ext_vector_type(2))) unsigned int u32x2;
typedef __attribute__((ext_vector_type(4))) unsigned short u16x4;

#define NB 4
#define NS 2048
#define NH 12
#define HD 64
#define ND 768
#define ND3 2304

// scale * log2(e) folded into Q at QKV epilogue
#define QSCALE 0.18033688f

// ---------- helpers ----------
__device__ __forceinline__ u16 f2bf(float f) {
    unsigned int u = __float_as_uint(f);
    unsigned int r = u + 0x7fffu + ((u >> 16) & 1u);
    return (u16)(r >> 16);
}

// async global->LDS, 16B per lane; LDS dest = wave-uniform base + lane*16B
__device__ __forceinline__ void gload16(const u16* g, u16* s) {
    __builtin_amdgcn_global_load_lds(
        (const __attribute__((address_space(1))) unsigned int*)(const void*)g,
        (__attribute__((address_space(3))) unsigned int*)(void*)s, 16, 0, 0);
}

__device__ __forceinline__ unsigned int cvtpk(float lo, float hi) {
    unsigned int pk;
    asm("v_cvt_pk_bf16_f32 %0, %1, %2" : "=v"(pk) : "v"(lo), "v"(hi));
    return pk;
}

// ---------- fused fp32 -> bf16 casts (x, W_qkv, W_out) ----------
#define XN4   1572864
#define WQN4  442368
#define WON4  147456
__global__ __launch_bounds__(256) void castall(const float* __restrict__ x,
                                               const float* __restrict__ wq,
                                               const float* __restrict__ wo,
                                               u16* __restrict__ xb,
                                               u16* __restrict__ wqb,
                                               u16* __restrict__ wob) {
    int i = blockIdx.x * 256 + threadIdx.x;
    const float* s; u16* d; int j;
    if (i < XN4) { s = x; d = xb; j = i; }
    else if (i < XN4 + WQN4) { s = wq; d = wqb; j = i - XN4; }
    else if (i < XN4 + WQN4 + WON4) { s = wo; d = wob; j = i - XN4 - WQN4; }
    else return;
    float4 v = ((const float4*)s)[j];
    ushort4 o;
    o.x = f2bf(v.x); o.y = f2bf(v.y); o.z = f2bf(v.z); o.w = f2bf(v.w);
    ((ushort4*)d)[j] = o;
}

// ---------- QKV GEMM: C[8192][2304] = x_bf16 @ Wqkv_bf16^T + b ----------
// R8 structure (BK=64, 128x192 tiles, 2 LDS bufs, counted schedule, 2/CU —
// best-measured 76.8 us) + R9 XCD swizzle (per-XCD hot set A 1.5 MB +
// B 2.35 MB < 4 MB L2) + NEW: non-temporal C-stores ('nt' bypasses L2).
// R11 diagnosis: staging runs at ~5 TB/s because the 41 MB C-write stream
// evicts the read hot set from L2 (m97 proves 28 TB/s staging when
// L2-resident). nt-stores keep A/B panels resident -> re-reads become
// L2 hits at 34 TB/s.
__global__ __launch_bounds__(256, 2) void gemm_qkv(const u16* __restrict__ A,
                                                   const u16* __restrict__ Bw,
                                                   const float* __restrict__ bias,
                                                   u16* __restrict__ Qg,
                                                   u16* __restrict__ Kg,
                                                   u16* __restrict__ Vtg) {
    __shared__ u16 lds[2][20480];
    const int tid = threadIdx.x;
    const int w = tid >> 6, l = tid & 63;
    const int lam = l & 15, quad = l >> 4;
    const int wm = w >> 1, wn = w & 1;
    // XCD swizzle: 768 blocks = 8 xcd x (8 xblk x 12 heads), xblk-fastest
    const int bid = blockIdx.x;
    const int xcd = bid & 7, local = bid >> 3;     // local in [0,96)
    const int xblk = local & 7, hh = local >> 3;   // xblk in [0,8), hh in [0,12)
    const int bm = (xcd * 8 + xblk) * 128;
    const int bn = hh * 192;
    const int NT = ND / 64;             // 12 K-steps

    f32x4 acc[4][6];
#pragma unroll
    for (int i = 0; i < 4; i++)
#pragma unroll
        for (int j = 0; j < 6; j++) { f32x4 z = {0.f, 0.f, 0.f, 0.f}; acc[i][j] = z; }

    const u16* gp[10];
    int so[10]; // wave-uniform chunk base (u16 units) within a buffer
#pragma unroll
    for (int i = 0; i < 10; i++) {
        int c = w * 10 + i;
        so[i] = c * 512;
        if (c < 16) {
            int rowgrp = c >> 1, ks = c & 1;
            gp[i] = A + (size_t)(bm + rowgrp * 16 + lam) * ND + ks * 32 + quad * 8;
        } else {
            int cc = c - 16, nf = cc >> 1, ks = cc & 1;
            gp[i] = Bw + (size_t)(bn + nf * 16 + lam) * ND + ks * 32 + quad * 8;
        }
    }

    // prologue: stage tile 0 into buf 0
#pragma unroll
    for (int i = 0; i < 10; i++) gload16(gp[i], &lds[0][so[i]]);

    for (int t = 0; t < NT; ++t) {
        // stage t was issued one full compute phase ago -> near-free wait
        asm volatile("s_waitcnt vmcnt(0)" ::: "memory");
        __builtin_amdgcn_s_barrier();
        asm volatile("" ::: "memory");
        if (t + 1 < NT) {
#pragma unroll
            for (int i = 0; i < 10; i++) gload16(gp[i] + (t + 1) * 64, &lds[(t + 1) & 1][so[i]]);
        }
        const u16* buf = lds[t & 1];
#pragma unroll
        for (int ks = 0; ks < 2; ks++) {
            short8 a[4];
#pragma unroll
            for (int i = 0; i < 4; i++) a[i] = *(const short8*)(buf + ((wm * 4 + i) * 2 + ks) * 512 + l * 8);
#pragma unroll
            for (int half = 0; half < 2; half++) {
                short8 b[3];
#pragma unroll
                for (int j = 0; j < 3; j++) b[j] = *(const short8*)(buf + (16 + (wn * 6 + half * 3 + j) * 2 + ks) * 512 + l * 8);
#pragma unroll
                for (int mf = 0; mf < 4; mf++)
#pragma unroll
                    for (int j = 0; j < 3; j++)
                        acc[mf][half * 3 + j] = __builtin_amdgcn_mfma_f32_16x16x32_bf16(a[mf], b[j], acc[mf][half * 3 + j], 0, 0, 0);
            }
        }
    }

    // epilogue (all stores non-temporal): C row m = bm + wm*64 + mf*16 + quad*4 + r;
    // local col = wn*96 + nf*16 + lam
#pragma unroll
    for (int nf = 0; nf < 6; nf++) {
        int nloc = wn * 96 + nf * 16;       // wave-uniform, multiple of 16
        int rgn = nloc / 64;                // 0:Q 1:K 2:V (uniform; lam<16 never crosses)
        int d = (nloc % 64) + lam;
        float bv = bias[bn + nloc + lam];
        if (rgn == 2) {
#pragma unroll
            for (int mf = 0; mf < 4; mf++) {
                int m0 = bm + wm * 64 + mf * 16 + quad * 4;
                int bq = m0 >> 11, s0 = m0 & 2047;
                u16x4 o;
                o.x = f2bf(acc[mf][nf][0] + bv);
                o.y = f2bf(acc[mf][nf][1] + bv);
                o.z = f2bf(acc[mf][nf][2] + bv);
                o.w = f2bf(acc[mf][nf][3] + bv);
                __builtin_nontemporal_store(o, (u16x4*)(Vtg + ((size_t)((bq * NH + hh) * HD + d)) * NS + s0));
            }
        } else {
            u16* dst = (rgn == 0) ? Qg : Kg;
            const float sc = (rgn == 0) ? QSCALE : 1.0f;
#pragma unroll
            for (int mf = 0; mf < 4; mf++)
#pragma unroll
                for (int r = 0; r < 4; r++) {
                    int m = bm + wm * 64 + mf * 16 + quad * 4 + r;
                    int bq = m >> 11, s = m & 2047;
                    __builtin_nontemporal_store(f2bf((acc[mf][nf][r] + bv) * sc),
                        dst + ((size_t)((bq * NH + hh) * NS + s)) * HD + d);
                }
        }
    }
}

// ---------- flash attention, P-in-register, full-rate PV via permlane32_swap ----------
// (R7 structure, unchanged — control.)
__global__ __launch_bounds__(256, 3) void attn(const u16* __restrict__ Qg,
                                               const u16* __restrict__ Kg,
                                               const u16* __restrict__ Vtg,
                                               u16* __restrict__ ctx) {
    // per buf: K chunks 0..7 (64 kpos x 64 d), V chunks 8..15 (Vt 64 hd x 64 t)
    __shared__ u16 kv_lds[3][8192];
    const int tid = threadIdx.x;
    const int w = tid >> 6, L = tid & 63;
    const int r5 = L & 31, h = L >> 5;
    const int bid = blockIdx.x;
    const int qt = bid / 48, bh = bid % 48;
    const int b = bh / NH, hd = bh % NH;
    const u16* Qh = Qg + (size_t)bh * NS * HD;
    const u16* Kh = Kg + (size_t)bh * NS * HD;
    const u16* Vh = Vtg + (size_t)bh * HD * NS;

    const int qbase = qt * 128 + w * 32;

    // Q B-frags (32x32x16): lane holds Q[q=r5][kd=s*16+h*8+0..7]
    short8 qf[4];
#pragma unroll
    for (int s = 0; s < 4; s++)
        qf[s] = *(const short8*)(Qh + (size_t)(qbase + r5) * HD + s * 16 + h * 8);

    f32x16 ot[2];
#pragma unroll
    for (int hg = 0; hg < 2; hg++)
#pragma unroll
        for (int r = 0; r < 16; r++) ot[hg][r] = 0.f;

    // row-sum accumulator (C-layout identical to ot rows); ones B-frag for P.1
    f32x16 lsum;
#pragma unroll
    for (int r = 0; r < 16; r++) lsum[r] = 0.f;
    short8 onesf;
#pragma unroll
    for (int i = 0; i < 8; i++) onesf[i] = (short)0x3F80;  // bf16 1.0

    // persistent zero C-operand for the QK mfma (laundered: stays in regs)
    f32x16 zero16;
#pragma unroll
    for (int r = 0; r < 16; r++) zero16[r] = 0.f;
    asm volatile("" : "+v"(zero16));

    // staging: 16 chunks / 4 waves = 4 chunks per wave.
    // waves 0-1: K chunks 0..7; waves 2-3: V chunks 8..15.
    const u16* gp[4];
    int so[4];
    int step;
    if (w < 2) {
#pragma unroll
        for (int i = 0; i < 4; i++) {
            int c = w * 4 + i;                 // 0..7
            int kg = c >> 2, s = c & 3;
            gp[i] = Kh + (size_t)(kg * 32 + r5) * HD + s * 16 + h * 8;
            so[i] = c * 512;
        }
        step = 64 * HD;
    } else {
#pragma unroll
        for (int i = 0; i < 4; i++) {
            int v = (w - 2) * 4 + i;           // 0..7
            int hg = v >> 2, tb = v & 3;
            gp[i] = Vh + (size_t)(hg * 32 + r5) * NS + tb * 16 + h * 8;
            so[i] = (8 + v) * 512;
        }
        step = 64;
    }

    const int NT = NS / 64;  // 32 tiles
    // prologue: stage tiles 0,1 into bufs 0,1 (8 loads in flight per wave)
#pragma unroll
    for (int t = 0; t < 2; t++)
#pragma unroll
        for (int i = 0; i < 4; i++) gload16(gp[i] + (size_t)t * step, &kv_lds[t][so[i]]);

    int cur = 0, nx2 = 2;   // kt%3 and (kt+2)%3, manually rotated
    for (int kt = 0; kt < NT; kt++) {
        // own stage-t loads done (stage t+1 stays in flight), then barrier:
        // all waves' tile-t chunks resident + all compute of t-1 finished.
        if (kt < NT - 1) asm volatile("s_waitcnt vmcnt(4)" ::: "memory");
        else             asm volatile("s_waitcnt vmcnt(0)" ::: "memory");
        __builtin_amdgcn_s_barrier();
        asm volatile("" ::: "memory");
        if (kt + 2 < NT) {
#pragma unroll
            for (int i = 0; i < 4; i++) gload16(gp[i] + (size_t)(kt + 2) * step, &kv_lds[nx2][so[i]]);
        }
        const u16* buf = kv_lds[cur];

#pragma unroll
        for (int kg = 0; kg < 2; kg++) {
            // QK^T: 4 chained MFMAs, first uses persistent zero C (no re-init)
            short8 kf0 = *(const short8*)(buf + (kg * 4 + 0) * 512 + L * 8);
            f32x16 st = __builtin_amdgcn_mfma_f32_32x32x16_bf16(kf0, qf[0], zero16, 0, 0, 0);
#pragma unroll
            for (int s = 1; s < 4; s++) {
                short8 kf = *(const short8*)(buf + (kg * 4 + s) * 512 + L * 8);
                st = __builtin_amdgcn_mfma_f32_32x32x16_bf16(kf, qf[s], st, 0, 0, 0);
            }

            // exp2 -> pack pairs to bf16 via v_cvt_pk_bf16_f32 (RNE)
            float e[16];
#pragma unroll
            for (int i = 0; i < 16; i++) e[i] = __builtin_amdgcn_exp2f(st[i]);
            unsigned int q8[8];
#pragma unroll
            for (int i = 0; i < 8; i++) q8[i] = cvtpk(e[2 * i], e[2 * i + 1]);

            // cross-lane half-swaps -> A-frags for the two 16-t blocks of this kg
            u32x2 s02 = __builtin_amdgcn_permlane32_swap(q8[0], q8[2], false, false);
            u32x2 s13 = __builtin_amdgcn_permlane32_swap(q8[1], q8[3], false, false);
            u32x2 s46 = __builtin_amdgcn_permlane32_swap(q8[4], q8[6], false, false);
            u32x2 s57 = __builtin_amdgcn_permlane32_swap(q8[5], q8[7], false, false);
            union { u32x4 u; short8 s; } af0, af1;
            af0.u = (u32x4){s02.x, s13.x, s02.y, s13.y};
            af1.u = (u32x4){s46.x, s57.x, s46.y, s57.y};

            // row-sums on the matrix pipe: l += P.1
            lsum = __builtin_amdgcn_mfma_f32_32x32x16_bf16(af0.s, onesf, lsum, 0, 0, 0);
            lsum = __builtin_amdgcn_mfma_f32_32x32x16_bf16(af1.s, onesf, lsum, 0, 0, 0);
#pragma unroll
            for (int hg = 0; hg < 2; hg++) {
                short8 vf0 = *(const short8*)(buf + (8 + hg * 4 + kg * 2 + 0) * 512 + L * 8);
                short8 vf1 = *(const short8*)(buf + (8 + hg * 4 + kg * 2 + 1) * 512 + L * 8);
                ot[hg] = __builtin_amdgcn_mfma_f32_32x32x16_bf16(af0.s, vf0, ot[hg], 0, 0, 0);
                ot[hg] = __builtin_amdgcn_mfma_f32_32x32x16_bf16(af1.s, vf1, ot[hg], 0, 0, 0);
            }
        }
        cur = (cur == 2) ? 0 : cur + 1;
        nx2 = (nx2 == 2) ? 0 : nx2 + 1;
    }

    // epilogue: O C-layout: col hd' = r5, row q' = (r&3)+8*(r>>2)+4*h
    // lsum has the same row layout (cols replicated) -> pure per-lane scale.
    float inv[16];
#pragma unroll
    for (int r = 0; r < 16; r++) inv[r] = __builtin_amdgcn_rcpf(lsum[r]);
#pragma unroll
    for (int hg = 0; hg < 2; hg++) {
#pragma unroll
        for (int r = 0; r < 16; r++) {
            int q = qbase + (r & 3) + 8 * (r >> 2) + 4 * h;
            ctx[(size_t)(b * NS + q) * ND + hd * HD + hg * 32 + r5] = f2bf(ot[hg][r] * inv[r]);
        }
    }
}

// ---------- out projection: out[8192][768] = ctx_bf16 @ Wout_bf16^T + b ----------
// R8 structure (BK=64, 128x96 tiles, 2 bufs) + XCD swizzle + non-temporal
// f32 output stores (out is never re-read; keep it out of L2 so ctx/W
// panels stay resident).
__global__ __launch_bounds__(256, 2) void gemm_out(const u16* __restrict__ A,
                                                   const u16* __restrict__ Bw,
                                                   const float* __restrict__ bias,
                                                   float* __restrict__ out) {
    __shared__ u16 lds[2][14336];
    const int tid = threadIdx.x;
    const int w = tid >> 6, l = tid & 63;
    const int lam = l & 15, quad = l >> 4;
    const int wm = w >> 1, wn = w & 1;
    // XCD swizzle: 512 blocks = 8 xcd x (8 xblk x 8 yblk), xblk-fastest
    const int bid = blockIdx.x;
    const int xcd = bid & 7, local = bid >> 3;     // local in [0,64)
    const int xblk = local & 7, yblk = local >> 3; // each in [0,8)
    const int bm = (xcd * 8 + xblk) * 128, bn = yblk * 96;
    const int NT = ND / 64;             // 12 K-steps

    f32x4 acc[4][3];
#pragma unroll
    for (int i = 0; i < 4; i++)
#pragma unroll
        for (int j = 0; j < 3; j++) { f32x4 z = {0.f, 0.f, 0.f, 0.f}; acc[i][j] = z; }

    const u16* gp[7];
    int so[7];
#pragma unroll
    for (int i = 0; i < 7; i++) {
        int c = w * 7 + i;
        so[i] = c * 512;
        if (c < 16) {
            int rowgrp = c >> 1, ks = c & 1;
            gp[i] = A + (size_t)(bm + rowgrp * 16 + lam) * ND + ks * 32 + quad * 8;
        } else {
            int cc = c - 16, nf = cc >> 1, ks = cc & 1;
            gp[i] = Bw + (size_t)(bn + nf * 16 + lam) * ND + ks * 32 + quad * 8;
        }
    }

    // prologue: stage tile 0 into buf 0
#pragma unroll
    for (int i = 0; i < 7; i++) gload16(gp[i], &lds[0][so[i]]);

    for (int t = 0; t < NT; ++t) {
        asm volatile("s_waitcnt vmcnt(0)" ::: "memory");
        __builtin_amdgcn_s_barrier();
        asm volatile("" ::: "memory");
        if (t + 1 < NT) {
#pragma unroll
            for (int i = 0; i < 7; i++) gload16(gp[i] + (t + 1) * 64, &lds[(t + 1) & 1][so[i]]);
        }
        const u16* buf = lds[t & 1];
#pragma unroll
        for (int ks = 0; ks < 2; ks++) {
            short8 a[4], b[3];
#pragma unroll
            for (int i = 0; i < 4; i++) a[i] = *(const short8*)(buf + ((wm * 4 + i) * 2 + ks) * 512 + l * 8);
#pragma unroll
            for (int j = 0; j < 3; j++) b[j] = *(const short8*)(buf + (16 + (wn * 3 + j) * 2 + ks) * 512 + l * 8);
#pragma unroll
            for (int mf = 0; mf < 4; mf++)
#pragma unroll
                for (int j = 0; j < 3; j++)
                    acc[mf][j] = __builtin_amdgcn_mfma_f32_16x16x32_bf16(a[mf], b[j], acc[mf][j], 0, 0, 0);
        }
    }

#pragma unroll
    for (int nf = 0; nf < 3; nf++) {
        int n = bn + wn * 48 + nf * 16 + lam;
        float bv = bias[n];
#pragma unroll
        for (int mf = 0; mf < 4; mf++)
#pragma unroll
            for (int r = 0; r < 4; r++) {
                int m = bm + wm * 64 + mf * 16 + quad * 4 + r;
                __builtin_nontemporal_store(acc[mf][nf][r] + bv, out + (size_t)m * ND + n);
            }
    }
}

extern "C" void kernel_launch(void* const* d_in, const int* in_sizes, int n_in,
                              void* d_out, int out_size, void* d_ws, size_t ws_size,
                              hipStream_t stream) {
    const float* x    = (const float*)d_in[0];
    const float* Wqkv = (const float*)d_in[1];
    const float* bqkv = (const float*)d_in[2];
    const float* Wout = (const float*)d_in[3];
    const float* bout = (const float*)d_in[4];
    float* out = (float*)d_out;

    // workspace carve (bf16 elements)
    u16* p = (u16*)d_ws;
    u16* xb    = p; p += 6291456;  // x bf16 [8192][768]
    u16* wqkvb = p; p += 1769472;  // Wqkv bf16 [2304][768]
    u16* wob   = p; p += 589824;   // Wout bf16 [768][768]
    u16* Qg    = p; p += 6291456;  // [B,H,S,64] (pre-scaled by QSCALE)
    u16* Kg    = p; p += 6291456;  // [B,H,S,64]
    u16* Vtg   = p; p += 6291456;  // [B,H,64,S]
    u16* ctx   = p; p += 6291456;  // [8192][768]

    castall<<<8448, 256, 0, stream>>>(x, Wqkv, Wout, xb, wqkvb, wob);
    gemm_qkv<<<768, 256, 0, stream>>>(xb, wqkvb, bqkv, Qg, Kg, Vtg);
    attn<<<768, 256, 0, stream>>>(Qg, Kg, Vtg, ctx);
    gemm_out<<<512, 256, 0, stream>>>(ctx, wob, bout, out);
}

// Round 13
// 222.423 us; speedup vs baseline: 1.0335x; 1.0335x over previous
//
#include <hip/hip_runtime.h>
#include <hip/hip_bf16.h>
#include <stdint.h>
#include <math.h>

typedef unsigned short u16;
typedef __attribute__((ext_vector_type(8))) short short8;
typedef __attribute__((ext_vector_type(4))) float f32x4;
typedef __attribute__((ext_vector_type(16))) float f32x16;
typedef __attribute__((ext_vector_type(4))) unsigned int u32x4;
typedef __attribute__((ext_vector_type(2))) unsigned int u32x2;

#define NB 4
#define NS 2048
#define NH 12
#define HD 64
#define ND 768
#define ND3 2304

// scale * log2(e) folded into Q at QKV epilogue
#define QSCALE 0.18033688f

// ---------- helpers ----------
__device__ __forceinline__ u16 f2bf(float f) {
    unsigned int u = __float_as_uint(f);
    unsigned int r = u + 0x7fffu + ((u >> 16) & 1u);
    return (u16)(r >> 16);
}

// async global->LDS, 16B per lane; LDS dest = wave-uniform base + lane*16B
__device__ __forceinline__ void gload16(const u16* g, u16* s) {
    __builtin_amdgcn_global_load_lds(
        (const __attribute__((address_space(1))) unsigned int*)(const void*)g,
        (__attribute__((address_space(3))) unsigned int*)(void*)s, 16, 0, 0);
}

__device__ __forceinline__ unsigned int cvtpk(float lo, float hi) {
    unsigned int pk;
    asm("v_cvt_pk_bf16_f32 %0, %1, %2" : "=v"(pk) : "v"(lo), "v"(hi));
    return pk;
}

// ---------- fused fp32 -> bf16 casts (x, W_qkv, W_out) ----------
#define XN4   1572864
#define WQN4  442368
#define WON4  147456
__global__ __launch_bounds__(256) void castall(const float* __restrict__ x,
                                               const float* __restrict__ wq,
                                               const float* __restrict__ wo,
                                               u16* __restrict__ xb,
                                               u16* __restrict__ wqb,
                                               u16* __restrict__ wob) {
    int i = blockIdx.x * 256 + threadIdx.x;
    const float* s; u16* d; int j;
    if (i < XN4) { s = x; d = xb; j = i; }
    else if (i < XN4 + WQN4) { s = wq; d = wqb; j = i - XN4; }
    else if (i < XN4 + WQN4 + WON4) { s = wo; d = wob; j = i - XN4 - WQN4; }
    else return;
    float4 v = ((const float4*)s)[j];
    ushort4 o;
    o.x = f2bf(v.x); o.y = f2bf(v.y); o.z = f2bf(v.z); o.w = f2bf(v.w);
    ((ushort4*)d)[j] = o;
}

// ---------- QKV GEMM: C[8192][2304] = x_bf16 @ Wqkv_bf16^T + b ----------
// R8 configuration restored exactly (best-measured family): 128x192 tiles,
// grid (64,12), BK=64, 2 LDS bufs, counted schedule (stage issued one full
// compute-phase before its vmcnt(0)), plain stores, plain grid.
__global__ __launch_bounds__(256, 2) void gemm_qkv(const u16* __restrict__ A,
                                                   const u16* __restrict__ Bw,
                                                   const float* __restrict__ bias,
                                                   u16* __restrict__ Qg,
                                                   u16* __restrict__ Kg,
                                                   u16* __restrict__ Vtg) {
    __shared__ u16 lds[2][20480];
    const int tid = threadIdx.x;
    const int w = tid >> 6, l = tid & 63;
    const int lam = l & 15, quad = l >> 4;
    const int wm = w >> 1, wn = w & 1;
    const int bm = blockIdx.x * 128;
    const int hh = blockIdx.y;          // head (192 cols per head)
    const int bn = hh * 192;
    const int NT = ND / 64;             // 12 K-steps

    f32x4 acc[4][6];
#pragma unroll
    for (int i = 0; i < 4; i++)
#pragma unroll
        for (int j = 0; j < 6; j++) { f32x4 z = {0.f, 0.f, 0.f, 0.f}; acc[i][j] = z; }

    const u16* gp[10];
    int so[10]; // wave-uniform chunk base (u16 units) within a buffer
#pragma unroll
    for (int i = 0; i < 10; i++) {
        int c = w * 10 + i;
        so[i] = c * 512;
        if (c < 16) {
            int rowgrp = c >> 1, ks = c & 1;
            gp[i] = A + (size_t)(bm + rowgrp * 16 + lam) * ND + ks * 32 + quad * 8;
        } else {
            int cc = c - 16, nf = cc >> 1, ks = cc & 1;
            gp[i] = Bw + (size_t)(bn + nf * 16 + lam) * ND + ks * 32 + quad * 8;
        }
    }

    // prologue: stage tile 0 into buf 0
#pragma unroll
    for (int i = 0; i < 10; i++) gload16(gp[i], &lds[0][so[i]]);

    for (int t = 0; t < NT; ++t) {
        // stage t was issued one full compute phase ago -> near-free wait
        asm volatile("s_waitcnt vmcnt(0)" ::: "memory");
        __builtin_amdgcn_s_barrier();
        asm volatile("" ::: "memory");
        if (t + 1 < NT) {
#pragma unroll
            for (int i = 0; i < 10; i++) gload16(gp[i] + (t + 1) * 64, &lds[(t + 1) & 1][so[i]]);
        }
        const u16* buf = lds[t & 1];
#pragma unroll
        for (int ks = 0; ks < 2; ks++) {
            short8 a[4];
#pragma unroll
            for (int i = 0; i < 4; i++) a[i] = *(const short8*)(buf + ((wm * 4 + i) * 2 + ks) * 512 + l * 8);
#pragma unroll
            for (int half = 0; half < 2; half++) {
                short8 b[3];
#pragma unroll
                for (int j = 0; j < 3; j++) b[j] = *(const short8*)(buf + (16 + (wn * 6 + half * 3 + j) * 2 + ks) * 512 + l * 8);
#pragma unroll
                for (int mf = 0; mf < 4; mf++)
#pragma unroll
                    for (int j = 0; j < 3; j++)
                        acc[mf][half * 3 + j] = __builtin_amdgcn_mfma_f32_16x16x32_bf16(a[mf], b[j], acc[mf][half * 3 + j], 0, 0, 0);
            }
        }
    }

    // epilogue: C row m = bm + wm*64 + mf*16 + quad*4 + r ; local col = wn*96 + nf*16 + lam
#pragma unroll
    for (int nf = 0; nf < 6; nf++) {
        int nloc = wn * 96 + nf * 16;       // wave-uniform, multiple of 16
        int rgn = nloc / 64;                // 0:Q 1:K 2:V (uniform; lam<16 never crosses)
        int d = (nloc % 64) + lam;
        float bv = bias[bn + nloc + lam];
        if (rgn == 2) {
#pragma unroll
            for (int mf = 0; mf < 4; mf++) {
                int m0 = bm + wm * 64 + mf * 16 + quad * 4;
                int bq = m0 >> 11, s0 = m0 & 2047;
                ushort4 o;
                o.x = f2bf(acc[mf][nf][0] + bv);
                o.y = f2bf(acc[mf][nf][1] + bv);
                o.z = f2bf(acc[mf][nf][2] + bv);
                o.w = f2bf(acc[mf][nf][3] + bv);
                *(ushort4*)(Vtg + ((size_t)((bq * NH + hh) * HD + d)) * NS + s0) = o;
            }
        } else {
            u16* dst = (rgn == 0) ? Qg : Kg;
            const float sc = (rgn == 0) ? QSCALE : 1.0f;
#pragma unroll
            for (int mf = 0; mf < 4; mf++)
#pragma unroll
                for (int r = 0; r < 4; r++) {
                    int m = bm + wm * 64 + mf * 16 + quad * 4 + r;
                    int bq = m >> 11, s = m & 2047;
                    dst[((size_t)((bq * NH + hh) * NS + s)) * HD + d] = f2bf((acc[mf][nf][r] + bv) * sc);
                }
        }
    }
}

// ---------- flash attention, QBLK=256 (8 waves), P-in-register ----------
// R12 diagnosis: attn is staging-supply-bound (393 MB / 66 us = 5.95 TB/s =
// the same fabric ceiling as the GEMMs). Lever: halve staged bytes. QBLK
// 128->256: 8 waves (512 thr) share each K/V tile, grid 384 -> K/V staged
// 393 -> 196 MB. Per-wave code identical to R7 (32 q-rows, same MFMA/
// softmax/staging idiom); now 2 chunks/wave, counted vmcnt(2), 3 LDS bufs.
__global__ __launch_bounds__(512, 2) void attn(const u16* __restrict__ Qg,
                                               const u16* __restrict__ Kg,
                                               const u16* __restrict__ Vtg,
                                               u16* __restrict__ ctx) {
    // per buf: K chunks 0..7 (64 kpos x 64 d), V chunks 8..15 (Vt 64 hd x 64 t)
    __shared__ u16 kv_lds[3][8192];
    const int tid = threadIdx.x;
    const int w = tid >> 6, L = tid & 63;       // w in [0,8)
    const int r5 = L & 31, h = L >> 5;
    const int bid = blockIdx.x;                 // 384 = 8 qt x 48 bh
    const int qt = bid / 48, bh = bid % 48;
    const int b = bh / NH, hd = bh % NH;
    const u16* Qh = Qg + (size_t)bh * NS * HD;
    const u16* Kh = Kg + (size_t)bh * NS * HD;
    const u16* Vh = Vtg + (size_t)bh * HD * NS;

    const int qbase = qt * 256 + w * 32;

    // Q B-frags (32x32x16): lane holds Q[q=r5][kd=s*16+h*8+0..7]
    short8 qf[4];
#pragma unroll
    for (int s = 0; s < 4; s++)
        qf[s] = *(const short8*)(Qh + (size_t)(qbase + r5) * HD + s * 16 + h * 8);

    f32x16 ot[2];
#pragma unroll
    for (int hg = 0; hg < 2; hg++)
#pragma unroll
        for (int r = 0; r < 16; r++) ot[hg][r] = 0.f;

    // row-sum accumulator (C-layout identical to ot rows); ones B-frag for P.1
    f32x16 lsum;
#pragma unroll
    for (int r = 0; r < 16; r++) lsum[r] = 0.f;
    short8 onesf;
#pragma unroll
    for (int i = 0; i < 8; i++) onesf[i] = (short)0x3F80;  // bf16 1.0

    // persistent zero C-operand for the QK mfma (laundered: stays in regs)
    f32x16 zero16;
#pragma unroll
    for (int r = 0; r < 16; r++) zero16[r] = 0.f;
    asm volatile("" : "+v"(zero16));

    // staging: 16 chunks / 8 waves = 2 chunks per wave.
    // waves 0-3: K chunks 0..7; waves 4-7: V chunks 8..15.
    const u16* gp[2];
    int so[2];
    int step;
    if (w < 4) {
#pragma unroll
        for (int i = 0; i < 2; i++) {
            int c = w * 2 + i;                 // 0..7
            int kg = c >> 2, s = c & 3;
            gp[i] = Kh + (size_t)(kg * 32 + r5) * HD + s * 16 + h * 8;
            so[i] = c * 512;
        }
        step = 64 * HD;
    } else {
#pragma unroll
        for (int i = 0; i < 2; i++) {
            int v = (w - 4) * 2 + i;           // 0..7
            int hg = v >> 2, tb = v & 3;
            gp[i] = Vh + (size_t)(hg * 32 + r5) * NS + tb * 16 + h * 8;
            so[i] = (8 + v) * 512;
        }
        step = 64;
    }

    const int NT = NS / 64;  // 32 tiles
    // prologue: stage tiles 0,1 into bufs 0,1 (4 loads in flight per wave)
#pragma unroll
    for (int t = 0; t < 2; t++)
#pragma unroll
        for (int i = 0; i < 2; i++) gload16(gp[i] + (size_t)t * step, &kv_lds[t][so[i]]);

    int cur = 0, nx2 = 2;   // kt%3 and (kt+2)%3, manually rotated
    for (int kt = 0; kt < NT; kt++) {
        // own stage-t loads done (stage t+1 stays in flight), then barrier:
        // all waves' tile-t chunks resident + all compute of t-1 finished.
        if (kt < NT - 1) asm volatile("s_waitcnt vmcnt(2)" ::: "memory");
        else             asm volatile("s_waitcnt vmcnt(0)" ::: "memory");
        __builtin_amdgcn_s_barrier();
        asm volatile("" ::: "memory");
        if (kt + 2 < NT) {
#pragma unroll
            for (int i = 0; i < 2; i++) gload16(gp[i] + (size_t)(kt + 2) * step, &kv_lds[nx2][so[i]]);
        }
        const u16* buf = kv_lds[cur];

#pragma unroll
        for (int kg = 0; kg < 2; kg++) {
            // QK^T: 4 chained MFMAs, first uses persistent zero C (no re-init)
            short8 kf0 = *(const short8*)(buf + (kg * 4 + 0) * 512 + L * 8);
            f32x16 st = __builtin_amdgcn_mfma_f32_32x32x16_bf16(kf0, qf[0], zero16, 0, 0, 0);
#pragma unroll
            for (int s = 1; s < 4; s++) {
                short8 kf = *(const short8*)(buf + (kg * 4 + s) * 512 + L * 8);
                st = __builtin_amdgcn_mfma_f32_32x32x16_bf16(kf, qf[s], st, 0, 0, 0);
            }

            // exp2 -> pack pairs to bf16 via v_cvt_pk_bf16_f32 (RNE)
            float e[16];
#pragma unroll
            for (int i = 0; i < 16; i++) e[i] = __builtin_amdgcn_exp2f(st[i]);
            unsigned int q8[8];
#pragma unroll
            for (int i = 0; i < 8; i++) q8[i] = cvtpk(e[2 * i], e[2 * i + 1]);

            // cross-lane half-swaps -> A-frags for the two 16-t blocks of this kg
            u32x2 s02 = __builtin_amdgcn_permlane32_swap(q8[0], q8[2], false, false);
            u32x2 s13 = __builtin_amdgcn_permlane32_swap(q8[1], q8[3], false, false);
            u32x2 s46 = __builtin_amdgcn_permlane32_swap(q8[4], q8[6], false, false);
            u32x2 s57 = __builtin_amdgcn_permlane32_swap(q8[5], q8[7], false, false);
            union { u32x4 u; short8 s; } af0, af1;
            af0.u = (u32x4){s02.x, s13.x, s02.y, s13.y};
            af1.u = (u32x4){s46.x, s57.x, s46.y, s57.y};

            // row-sums on the matrix pipe: l += P.1
            lsum = __builtin_amdgcn_mfma_f32_32x32x16_bf16(af0.s, onesf, lsum, 0, 0, 0);
            lsum = __builtin_amdgcn_mfma_f32_32x32x16_bf16(af1.s, onesf, lsum, 0, 0, 0);
#pragma unroll
            for (int hg = 0; hg < 2; hg++) {
                short8 vf0 = *(const short8*)(buf + (8 + hg * 4 + kg * 2 + 0) * 512 + L * 8);
                short8 vf1 = *(const short8*)(buf + (8 + hg * 4 + kg * 2 + 1) * 512 + L * 8);
                ot[hg] = __builtin_amdgcn_mfma_f32_32x32x16_bf16(af0.s, vf0, ot[hg], 0, 0, 0);
                ot[hg] = __builtin_amdgcn_mfma_f32_32x32x16_bf16(af1.s, vf1, ot[hg], 0, 0, 0);
            }
        }
        cur = (cur == 2) ? 0 : cur + 1;
        nx2 = (nx2 == 2) ? 0 : nx2 + 1;
    }

    // epilogue: O C-layout: col hd' = r5, row q' = (r&3)+8*(r>>2)+4*h
    // lsum has the same row layout (cols replicated) -> pure per-lane scale.
    float inv[16];
#pragma unroll
    for (int r = 0; r < 16; r++) inv[r] = __builtin_amdgcn_rcpf(lsum[r]);
#pragma unroll
    for (int hg = 0; hg < 2; hg++) {
#pragma unroll
        for (int r = 0; r < 16; r++) {
            int q = qbase + (r & 3) + 8 * (r >> 2) + 4 * h;
            ctx[(size_t)(b * NS + q) * ND + hd * HD + hg * 32 + r5] = f2bf(ot[hg][r] * inv[r]);
        }
    }
}

// ---------- out projection: out[8192][768] = ctx_bf16 @ Wout_bf16^T + b ----------
// R8 configuration restored exactly: 128x96 tiles, grid (64,8), BK=64,
// 2 LDS bufs, counted schedule, plain stores.
__global__ __launch_bounds__(256, 2) void gemm_out(const u16* __restrict__ A,
                                                   const u16* __restrict__ Bw,
                                                   const float* __restrict__ bias,
                                                   float* __restrict__ out) {
    __shared__ u16 lds[2][14336];
    const int tid = threadIdx.x;
    const int w = tid >> 6, l = tid & 63;
    const int lam = l & 15, quad = l >> 4;
    const int wm = w >> 1, wn = w & 1;
    const int bm = blockIdx.x * 128, bn = blockIdx.y * 96;
    const int NT = ND / 64;             // 12 K-steps

    f32x4 acc[4][3];
#pragma unroll
    for (int i = 0; i < 4; i++)
#pragma unroll
        for (int j = 0; j < 3; j++) { f32x4 z = {0.f, 0.f, 0.f, 0.f}; acc[i][j] = z; }

    const u16* gp[7];
    int so[7];
#pragma unroll
    for (int i = 0; i < 7; i++) {
        int c = w * 7 + i;
        so[i] = c * 512;
        if (c < 16) {
            int rowgrp = c >> 1, ks = c & 1;
            gp[i] = A + (size_t)(bm + rowgrp * 16 + lam) * ND + ks * 32 + quad * 8;
        } else {
            int cc = c - 16, nf = cc >> 1, ks = cc & 1;
            gp[i] = Bw + (size_t)(bn + nf * 16 + lam) * ND + ks * 32 + quad * 8;
        }
    }

    // prologue: stage tile 0 into buf 0
#pragma unroll
    for (int i = 0; i < 7; i++) gload16(gp[i], &lds[0][so[i]]);

    for (int t = 0; t < NT; ++t) {
        asm volatile("s_waitcnt vmcnt(0)" ::: "memory");
        __builtin_amdgcn_s_barrier();
        asm volatile("" ::: "memory");
        if (t + 1 < NT) {
#pragma unroll
            for (int i = 0; i < 7; i++) gload16(gp[i] + (t + 1) * 64, &lds[(t + 1) & 1][so[i]]);
        }
        const u16* buf = lds[t & 1];
#pragma unroll
        for (int ks = 0; ks < 2; ks++) {
            short8 a[4], b[3];
#pragma unroll
            for (int i = 0; i < 4; i++) a[i] = *(const short8*)(buf + ((wm * 4 + i) * 2 + ks) * 512 + l * 8);
#pragma unroll
            for (int j = 0; j < 3; j++) b[j] = *(const short8*)(buf + (16 + (wn * 3 + j) * 2 + ks) * 512 + l * 8);
#pragma unroll
            for (int mf = 0; mf < 4; mf++)
#pragma unroll
                for (int j = 0; j < 3; j++)
                    acc[mf][j] = __builtin_amdgcn_mfma_f32_16x16x32_bf16(a[mf], b[j], acc[mf][j], 0, 0, 0);
        }
    }

#pragma unroll
    for (int nf = 0; nf < 3; nf++) {
        int n = bn + wn * 48 + nf * 16 + lam;
        float bv = bias[n];
#pragma unroll
        for (int mf = 0; mf < 4; mf++)
#pragma unroll
            for (int r = 0; r < 4; r++) {
                int m = bm + wm * 64 + mf * 16 + quad * 4 + r;
                out[(size_t)m * ND + n] = acc[mf][nf][r] + bv;
            }
    }
}

extern "C" void kernel_launch(void* const* d_in, const int* in_sizes, int n_in,
                              void* d_out, int out_size, void* d_ws, size_t ws_size,
                              hipStream_t stream) {
    const float* x    = (const float*)d_in[0];
    const float* Wqkv = (const float*)d_in[1];
    const float* bqkv = (const float*)d_in[2];
    const float* Wout = (const float*)d_in[3];
    const float* bout = (const float*)d_in[4];
    float* out = (float*)d_out;

    // workspace carve (bf16 elements)
    u16* p = (u16*)d_ws;
    u16* xb    = p; p += 6291456;  // x bf16 [8192][768]
    u16* wqkvb = p; p += 1769472;  // Wqkv bf16 [2304][768]
    u16* wob   = p; p += 589824;   // Wout bf16 [768][768]
    u16* Qg    = p; p += 6291456;  // [B,H,S,64] (pre-scaled by QSCALE)
    u16* Kg    = p; p += 6291456;  // [B,H,S,64]
    u16* Vtg   = p; p += 6291456;  // [B,H,64,S]
    u16* ctx   = p; p += 6291456;  // [8192][768]

    castall<<<8448, 256, 0, stream>>>(x, Wqkv, Wout, xb, wqkvb, wob);
    gemm_qkv<<<dim3(64, 12), 256, 0, stream>>>(xb, wqkvb, bqkv, Qg, Kg, Vtg);
    attn<<<384, 512, 0, stream>>>(Qg, Kg, Vtg, ctx);
    gemm_out<<<dim3(64, 8), 256, 0, stream>>>(ctx, wob, bout, out);
}

// Round 14
// 218.352 us; speedup vs baseline: 1.0527x; 1.0186x over previous
//
#include <hip/hip_runtime.h>
#include <hip/hip_bf16.h>
#include <stdint.h>
#include <math.h>

typedef unsigned short u16;
typedef __attribute__((ext_vector_type(8))) short short8;
typedef __attribute__((ext_vector_type(4))) float f32x4;
typedef __attribute__((ext_vector_type(16))) float f32x16;
typedef __attribute__((ext_vector_type(4))) unsigned int u32x4;
typedef __attribute__((ext_vector_type(2))) unsigned int u32x2;

#define NB 4
#define NS 2048
#define NH 12
#define HD 64
#define ND 768
#define ND3 2304

// scale * log2(e) folded into Q at QKV epilogue
#define QSCALE 0.18033688f

// ---------- helpers ----------
__device__ __forceinline__ u16 f2bf(float f) {
    unsigned int u = __float_as_uint(f);
    unsigned int r = u + 0x7fffu + ((u >> 16) & 1u);
    return (u16)(r >> 16);
}

// async global->LDS, 16B per lane; LDS dest = wave-uniform base + lane*16B
__device__ __forceinline__ void gload16(const u16* g, u16* s) {
    __builtin_amdgcn_global_load_lds(
        (const __attribute__((address_space(1))) unsigned int*)(const void*)g,
        (__attribute__((address_space(3))) unsigned int*)(void*)s, 16, 0, 0);
}

__device__ __forceinline__ unsigned int cvtpk(float lo, float hi) {
    unsigned int pk;
    asm("v_cvt_pk_bf16_f32 %0, %1, %2" : "=v"(pk) : "v"(lo), "v"(hi));
    return pk;
}

// ---------- fused fp32 -> bf16 casts (x, W_qkv, W_out) ----------
#define XN4   1572864
#define WQN4  442368
#define WON4  147456
__global__ __launch_bounds__(256) void castall(const float* __restrict__ x,
                                               const float* __restrict__ wq,
                                               const float* __restrict__ wo,
                                               u16* __restrict__ xb,
                                               u16* __restrict__ wqb,
                                               u16* __restrict__ wob) {
    int i = blockIdx.x * 256 + threadIdx.x;
    const float* s; u16* d; int j;
    if (i < XN4) { s = x; d = xb; j = i; }
    else if (i < XN4 + WQN4) { s = wq; d = wqb; j = i - XN4; }
    else if (i < XN4 + WQN4 + WON4) { s = wo; d = wob; j = i - XN4 - WQN4; }
    else return;
    float4 v = ((const float4*)s)[j];
    ushort4 o;
    o.x = f2bf(v.x); o.y = f2bf(v.y); o.z = f2bf(v.z); o.w = f2bf(v.w);
    ((ushort4*)d)[j] = o;
}

// ---------- QKV GEMM: C[8192][2304] = x_bf16 @ Wqkv_bf16^T + b ----------
// R8 K-loop (128x192 tiles, grid (64,12), BK=64, 2 LDS bufs, counted
// schedule) + NEW COALESCED EPILOGUE. R13 diagnosis: the epilogue was the
// one invariant across all six ~77us variants. Old stores: V = 64x 8B txns
// 4KB apart per instruction; Q/K = scalar 2B stores (32B segments) — ~2.25M
// L2 transactions/kernel. New: fragments re-staged into LDS
// (ctqk[128][136] for Q|K cols, ctv[64][140] pre-transposed V), then 24
// flush passes of 8B LDS read -> 8B store where consecutive lanes form
// 128-256B segments (txns /16). Bias/scale applied at LDS-write: values
// bit-identical.
__global__ __launch_bounds__(256, 2) void gemm_qkv(const u16* __restrict__ A,
                                                   const u16* __restrict__ Bw,
                                                   const float* __restrict__ bias,
                                                   u16* __restrict__ Qg,
                                                   u16* __restrict__ Kg,
                                                   u16* __restrict__ Vtg) {
    __shared__ u16 lds[2][20480];   // 80KB: staging bufs; reused as C-tile in epilogue
    const int tid = threadIdx.x;
    const int w = tid >> 6, l = tid & 63;
    const int lam = l & 15, quad = l >> 4;
    const int wm = w >> 1, wn = w & 1;
    const int bm = blockIdx.x * 128;
    const int hh = blockIdx.y;          // head (192 cols per head)
    const int bn = hh * 192;
    const int NT = ND / 64;             // 12 K-steps

    f32x4 acc[4][6];
#pragma unroll
    for (int i = 0; i < 4; i++)
#pragma unroll
        for (int j = 0; j < 6; j++) { f32x4 z = {0.f, 0.f, 0.f, 0.f}; acc[i][j] = z; }

    const u16* gp[10];
    int so[10]; // wave-uniform chunk base (u16 units) within a buffer
#pragma unroll
    for (int i = 0; i < 10; i++) {
        int c = w * 10 + i;
        so[i] = c * 512;
        if (c < 16) {
            int rowgrp = c >> 1, ks = c & 1;
            gp[i] = A + (size_t)(bm + rowgrp * 16 + lam) * ND + ks * 32 + quad * 8;
        } else {
            int cc = c - 16, nf = cc >> 1, ks = cc & 1;
            gp[i] = Bw + (size_t)(bn + nf * 16 + lam) * ND + ks * 32 + quad * 8;
        }
    }

    // prologue: stage tile 0 into buf 0
#pragma unroll
    for (int i = 0; i < 10; i++) gload16(gp[i], &lds[0][so[i]]);

    for (int t = 0; t < NT; ++t) {
        // stage t was issued one full compute phase ago -> near-free wait
        asm volatile("s_waitcnt vmcnt(0)" ::: "memory");
        __builtin_amdgcn_s_barrier();
        asm volatile("" ::: "memory");
        if (t + 1 < NT) {
#pragma unroll
            for (int i = 0; i < 10; i++) gload16(gp[i] + (t + 1) * 64, &lds[(t + 1) & 1][so[i]]);
        }
        const u16* buf = lds[t & 1];
#pragma unroll
        for (int ks = 0; ks < 2; ks++) {
            short8 a[4];
#pragma unroll
            for (int i = 0; i < 4; i++) a[i] = *(const short8*)(buf + ((wm * 4 + i) * 2 + ks) * 512 + l * 8);
#pragma unroll
            for (int half = 0; half < 2; half++) {
                short8 b[3];
#pragma unroll
                for (int j = 0; j < 3; j++) b[j] = *(const short8*)(buf + (16 + (wn * 6 + half * 3 + j) * 2 + ks) * 512 + l * 8);
#pragma unroll
                for (int mf = 0; mf < 4; mf++)
#pragma unroll
                    for (int j = 0; j < 3; j++)
                        acc[mf][half * 3 + j] = __builtin_amdgcn_mfma_f32_16x16x32_bf16(a[mf], b[j], acc[mf][half * 3 + j], 0, 0, 0);
            }
        }
    }

    // ---- coalesced epilogue: stage C tile in LDS, flush with 8B stores ----
    u16* ctqk = &lds[0][0];             // [128][stride 136]: cols 0..63 Q, 64..127 K
    u16* ctv  = &lds[0][0] + 128 * 136; // [64][stride 140]: ctv[d][s_local] (V^T)
    __syncthreads();                    // staging LDS no longer needed by any wave

#pragma unroll
    for (int nf = 0; nf < 6; nf++) {
        int nloc = wn * 96 + nf * 16;   // wave-uniform, multiple of 16
        int rgn = nloc / 64;            // 0:Q 1:K 2:V
        float bv = bias[bn + nloc + lam];
        if (rgn == 2) {
            int d = (nloc - 128) + lam; // 0..63
#pragma unroll
            for (int mf = 0; mf < 4; mf++) {
                int s_local = wm * 64 + mf * 16 + quad * 4;
                ushort4 o;
                o.x = f2bf(acc[mf][nf][0] + bv);
                o.y = f2bf(acc[mf][nf][1] + bv);
                o.z = f2bf(acc[mf][nf][2] + bv);
                o.w = f2bf(acc[mf][nf][3] + bv);
                *(ushort4*)(ctv + d * 140 + s_local) = o;
            }
        } else {
            int col = nloc + lam;       // 0..127
            const float sc = (rgn == 0) ? QSCALE : 1.0f;
#pragma unroll
            for (int mf = 0; mf < 4; mf++)
#pragma unroll
                for (int r = 0; r < 4; r++) {
                    int row = wm * 64 + mf * 16 + quad * 4 + r;
                    ctqk[row * 136 + col] = f2bf((acc[mf][nf][r] + bv) * sc);
                }
        }
    }
    __syncthreads();

    // flush: 8 passes x 3 regions; consecutive lanes -> 128B (Q/K) / 256B (V) segments
    const int bq = bm >> 11, s0g = bm & 2047;
    const size_t qkbase = ((size_t)(bq * NH + hh) * NS + s0g) * HD;
    const size_t vbase  = ((size_t)(bq * NH + hh) * HD) * NS + s0g;
#pragma unroll
    for (int p = 0; p < 8; p++) {
        int li = p * 256 + tid;
        {   // Q: rows 0..127, 16x 8B units per row
            int row = li >> 4, u = li & 15;
            ushort4 v = *(const ushort4*)(ctqk + row * 136 + u * 4);
            *(ushort4*)(Qg + qkbase + (size_t)row * HD + u * 4) = v;
        }
        {   // K
            int row = li >> 4, u = li & 15;
            ushort4 v = *(const ushort4*)(ctqk + row * 136 + 64 + u * 4);
            *(ushort4*)(Kg + qkbase + (size_t)row * HD + u * 4) = v;
        }
        {   // V^T: rows d 0..63, 32x 8B units per row
            int d = li >> 5, u = li & 31;
            ushort4 v = *(const ushort4*)(ctv + d * 140 + u * 4);
            *(ushort4*)(Vtg + vbase + (size_t)d * NS + u * 4) = v;
        }
    }
}

// ---------- flash attention, P-in-register, full-rate PV via permlane32_swap ----------
// (R7 structure exactly — best measured 66.0 us.)
__global__ __launch_bounds__(256, 3) void attn(const u16* __restrict__ Qg,
                                               const u16* __restrict__ Kg,
                                               const u16* __restrict__ Vtg,
                                               u16* __restrict__ ctx) {
    // per buf: K chunks 0..7 (64 kpos x 64 d), V chunks 8..15 (Vt 64 hd x 64 t)
    __shared__ u16 kv_lds[3][8192];
    const int tid = threadIdx.x;
    const int w = tid >> 6, L = tid & 63;
    const int r5 = L & 31, h = L >> 5;
    const int bid = blockIdx.x;
    const int qt = bid / 48, bh = bid % 48;
    const int b = bh / NH, hd = bh % NH;
    const u16* Qh = Qg + (size_t)bh * NS * HD;
    const u16* Kh = Kg + (size_t)bh * NS * HD;
    const u16* Vh = Vtg + (size_t)bh * HD * NS;

    const int qbase = qt * 128 + w * 32;

    // Q B-frags (32x32x16): lane holds Q[q=r5][kd=s*16+h*8+0..7]
    short8 qf[4];
#pragma unroll
    for (int s = 0; s < 4; s++)
        qf[s] = *(const short8*)(Qh + (size_t)(qbase + r5) * HD + s * 16 + h * 8);

    f32x16 ot[2];
#pragma unroll
    for (int hg = 0; hg < 2; hg++)
#pragma unroll
        for (int r = 0; r < 16; r++) ot[hg][r] = 0.f;

    // row-sum accumulator (C-layout identical to ot rows); ones B-frag for P.1
    f32x16 lsum;
#pragma unroll
    for (int r = 0; r < 16; r++) lsum[r] = 0.f;
    short8 onesf;
#pragma unroll
    for (int i = 0; i < 8; i++) onesf[i] = (short)0x3F80;  // bf16 1.0

    // persistent zero C-operand for the QK mfma (laundered: stays in regs)
    f32x16 zero16;
#pragma unroll
    for (int r = 0; r < 16; r++) zero16[r] = 0.f;
    asm volatile("" : "+v"(zero16));

    // staging: 16 chunks / 4 waves = 4 chunks per wave.
    // waves 0-1: K chunks 0..7; waves 2-3: V chunks 8..15.
    const u16* gp[4];
    int so[4];
    int step;
    if (w < 2) {
#pragma unroll
        for (int i = 0; i < 4; i++) {
            int c = w * 4 + i;                 // 0..7
            int kg = c >> 2, s = c & 3;
            gp[i] = Kh + (size_t)(kg * 32 + r5) * HD + s * 16 + h * 8;
            so[i] = c * 512;
        }
        step = 64 * HD;
    } else {
#pragma unroll
        for (int i = 0; i < 4; i++) {
            int v = (w - 2) * 4 + i;           // 0..7
            int hg = v >> 2, tb = v & 3;
            gp[i] = Vh + (size_t)(hg * 32 + r5) * NS + tb * 16 + h * 8;
            so[i] = (8 + v) * 512;
        }
        step = 64;
    }

    const int NT = NS / 64;  // 32 tiles
    // prologue: stage tiles 0,1 into bufs 0,1 (8 loads in flight per wave)
#pragma unroll
    for (int t = 0; t < 2; t++)
#pragma unroll
        for (int i = 0; i < 4; i++) gload16(gp[i] + (size_t)t * step, &kv_lds[t][so[i]]);

    int cur = 0, nx2 = 2;   // kt%3 and (kt+2)%3, manually rotated
    for (int kt = 0; kt < NT; kt++) {
        // own stage-t loads done (stage t+1 stays in flight), then barrier:
        // all waves' tile-t chunks resident + all compute of t-1 finished.
        if (kt < NT - 1) asm volatile("s_waitcnt vmcnt(4)" ::: "memory");
        else             asm volatile("s_waitcnt vmcnt(0)" ::: "memory");
        __builtin_amdgcn_s_barrier();
        asm volatile("" ::: "memory");
        if (kt + 2 < NT) {
#pragma unroll
            for (int i = 0; i < 4; i++) gload16(gp[i] + (size_t)(kt + 2) * step, &kv_lds[nx2][so[i]]);
        }
        const u16* buf = kv_lds[cur];

#pragma unroll
        for (int kg = 0; kg < 2; kg++) {
            // QK^T: 4 chained MFMAs, first uses persistent zero C (no re-init)
            short8 kf0 = *(const short8*)(buf + (kg * 4 + 0) * 512 + L * 8);
            f32x16 st = __builtin_amdgcn_mfma_f32_32x32x16_bf16(kf0, qf[0], zero16, 0, 0, 0);
#pragma unroll
            for (int s = 1; s < 4; s++) {
                short8 kf = *(const short8*)(buf + (kg * 4 + s) * 512 + L * 8);
                st = __builtin_amdgcn_mfma_f32_32x32x16_bf16(kf, qf[s], st, 0, 0, 0);
            }

            // exp2 -> pack pairs to bf16 via v_cvt_pk_bf16_f32 (RNE)
            float e[16];
#pragma unroll
            for (int i = 0; i < 16; i++) e[i] = __builtin_amdgcn_exp2f(st[i]);
            unsigned int q8[8];
#pragma unroll
            for (int i = 0; i < 8; i++) q8[i] = cvtpk(e[2 * i], e[2 * i + 1]);

            // cross-lane half-swaps -> A-frags for the two 16-t blocks of this kg
            u32x2 s02 = __builtin_amdgcn_permlane32_swap(q8[0], q8[2], false, false);
            u32x2 s13 = __builtin_amdgcn_permlane32_swap(q8[1], q8[3], false, false);
            u32x2 s46 = __builtin_amdgcn_permlane32_swap(q8[4], q8[6], false, false);
            u32x2 s57 = __builtin_amdgcn_permlane32_swap(q8[5], q8[7], false, false);
            union { u32x4 u; short8 s; } af0, af1;
            af0.u = (u32x4){s02.x, s13.x, s02.y, s13.y};
            af1.u = (u32x4){s46.x, s57.x, s46.y, s57.y};

            // row-sums on the matrix pipe: l += P.1
            lsum = __builtin_amdgcn_mfma_f32_32x32x16_bf16(af0.s, onesf, lsum, 0, 0, 0);
            lsum = __builtin_amdgcn_mfma_f32_32x32x16_bf16(af1.s, onesf, lsum, 0, 0, 0);
#pragma unroll
            for (int hg = 0; hg < 2; hg++) {
                short8 vf0 = *(const short8*)(buf + (8 + hg * 4 + kg * 2 + 0) * 512 + L * 8);
                short8 vf1 = *(const short8*)(buf + (8 + hg * 4 + kg * 2 + 1) * 512 + L * 8);
                ot[hg] = __builtin_amdgcn_mfma_f32_32x32x16_bf16(af0.s, vf0, ot[hg], 0, 0, 0);
                ot[hg] = __builtin_amdgcn_mfma_f32_32x32x16_bf16(af1.s, vf1, ot[hg], 0, 0, 0);
            }
        }
        cur = (cur == 2) ? 0 : cur + 1;
        nx2 = (nx2 == 2) ? 0 : nx2 + 1;
    }

    // epilogue: O C-layout: col hd' = r5, row q' = (r&3)+8*(r>>2)+4*h
    // lsum has the same row layout (cols replicated) -> pure per-lane scale.
    float inv[16];
#pragma unroll
    for (int r = 0; r < 16; r++) inv[r] = __builtin_amdgcn_rcpf(lsum[r]);
#pragma unroll
    for (int hg = 0; hg < 2; hg++) {
#pragma unroll
        for (int r = 0; r < 16; r++) {
            int q = qbase + (r & 3) + 8 * (r >> 2) + 4 * h;
            ctx[(size_t)(b * NS + q) * ND + hd * HD + hg * 32 + r5] = f2bf(ot[hg][r] * inv[r]);
        }
    }
}

// ---------- out projection: out[8192][768] = ctx_bf16 @ Wout_bf16^T + b ----------
// R8 configuration exactly: 128x96 tiles, grid (64,8), BK=64, 2 LDS bufs,
// counted schedule, plain stores (already 64B-segmented f32).
__global__ __launch_bounds__(256, 2) void gemm_out(const u16* __restrict__ A,
                                                   const u16* __restrict__ Bw,
                                                   const float* __restrict__ bias,
                                                   float* __restrict__ out) {
    __shared__ u16 lds[2][14336];
    const int tid = threadIdx.x;
    const int w = tid >> 6, l = tid & 63;
    const int lam = l & 15, quad = l >> 4;
    const int wm = w >> 1, wn = w & 1;
    const int bm = blockIdx.x * 128, bn = blockIdx.y * 96;
    const int NT = ND / 64;             // 12 K-steps

    f32x4 acc[4][3];
#pragma unroll
    for (int i = 0; i < 4; i++)
#pragma unroll
        for (int j = 0; j < 3; j++) { f32x4 z = {0.f, 0.f, 0.f, 0.f}; acc[i][j] = z; }

    const u16* gp[7];
    int so[7];
#pragma unroll
    for (int i = 0; i < 7; i++) {
        int c = w * 7 + i;
        so[i] = c * 512;
        if (c < 16) {
            int rowgrp = c >> 1, ks = c & 1;
            gp[i] = A + (size_t)(bm + rowgrp * 16 + lam) * ND + ks * 32 + quad * 8;
        } else {
            int cc = c - 16, nf = cc >> 1, ks = cc & 1;
            gp[i] = Bw + (size_t)(bn + nf * 16 + lam) * ND + ks * 32 + quad * 8;
        }
    }

    // prologue: stage tile 0 into buf 0
#pragma unroll
    for (int i = 0; i < 7; i++) gload16(gp[i], &lds[0][so[i]]);

    for (int t = 0; t < NT; ++t) {
        asm volatile("s_waitcnt vmcnt(0)" ::: "memory");
        __builtin_amdgcn_s_barrier();
        asm volatile("" ::: "memory");
        if (t + 1 < NT) {
#pragma unroll
            for (int i = 0; i < 7; i++) gload16(gp[i] + (t + 1) * 64, &lds[(t + 1) & 1][so[i]]);
        }
        const u16* buf = lds[t & 1];
#pragma unroll
        for (int ks = 0; ks < 2; ks++) {
            short8 a[4], b[3];
#pragma unroll
            for (int i = 0; i < 4; i++) a[i] = *(const short8*)(buf + ((wm * 4 + i) * 2 + ks) * 512 + l * 8);
#pragma unroll
            for (int j = 0; j < 3; j++) b[j] = *(const short8*)(buf + (16 + (wn * 3 + j) * 2 + ks) * 512 + l * 8);
#pragma unroll
            for (int mf = 0; mf < 4; mf++)
#pragma unroll
                for (int j = 0; j < 3; j++)
                    acc[mf][j] = __builtin_amdgcn_mfma_f32_16x16x32_bf16(a[mf], b[j], acc[mf][j], 0, 0, 0);
        }
    }

#pragma unroll
    for (int nf = 0; nf < 3; nf++) {
        int n = bn + wn * 48 + nf * 16 + lam;
        float bv = bias[n];
#pragma unroll
        for (int mf = 0; mf < 4; mf++)
#pragma unroll
            for (int r = 0; r < 4; r++) {
                int m = bm + wm * 64 + mf * 16 + quad * 4 + r;
                out[(size_t)m * ND + n] = acc[mf][nf][r] + bv;
            }
    }
}

extern "C" void kernel_launch(void* const* d_in, const int* in_sizes, int n_in,
                              void* d_out, int out_size, void* d_ws, size_t ws_size,
                              hipStream_t stream) {
    const float* x    = (const float*)d_in[0];
    const float* Wqkv = (const float*)d_in[1];
    const float* bqkv = (const float*)d_in[2];
    const float* Wout = (const float*)d_in[3];
    const float* bout = (const float*)d_in[4];
    float* out = (float*)d_out;

    // workspace carve (bf16 elements)
    u16* p = (u16*)d_ws;
    u16* xb    = p; p += 6291456;  // x bf16 [8192][768]
    u16* wqkvb = p; p += 1769472;  // Wqkv bf16 [2304][768]
    u16* wob   = p; p += 589824;   // Wout bf16 [768][768]
    u16* Qg    = p; p += 6291456;  // [B,H,S,64] (pre-scaled by QSCALE)
    u16* Kg    = p; p += 6291456;  // [B,H,S,64]
    u16* Vtg   = p; p += 6291456;  // [B,H,64,S]
    u16* ctx   = p; p += 6291456;  // [8192][768]

    castall<<<8448, 256, 0, stream>>>(x, Wqkv, Wout, xb, wqkvb, wob);
    gemm_qkv<<<dim3(64, 12), 256, 0, stream>>>(xb, wqkvb, bqkv, Qg, Kg, Vtg);
    attn<<<768, 256, 0, stream>>>(Qg, Kg, Vtg, ctx);
    gemm_out<<<dim3(64, 8), 256, 0, stream>>>(ctx, wob, bout, out);
}